// Round 1
// baseline (268.312 us; speedup 1.0000x reference)
//
#include <hip/hip_runtime.h>
#include <cmath>

#define NB   2048
#define ND   512
#define NL   8
#define NLAB 128
#define MAXM 64
#define TOPK_ 5
#define NTH  256

// ---------------------------------------------------------------------------
// R12: full per-label fusion. Previous 4-kernel chain was neither memory- nor
// compute-bound (work ~34MB / ~0.5GFLOP vs 131us): it paid 3 dependent launch
// gaps + G (16.7MB) written then re-read twice + Mbits/ema round-trip. All of
// that is label-local -> one block per label does gram(8 layers) + phase-1 +
// decide(8) + pairs(7) entirely in LDS (~122KB, 1 block/CU, 128 blocks).
// Only the 7x128 (n,d,cc) partials hit global; k_final keeps the exact
// cross-label ratio + summation order of the passing kernel (bit-match).
//
// Gram compute: 2x2 output tiles (4 row-streams feed 4 dots) halves LDS read
// amplification vs per-pair; per-pair FMA order (x,z->a / y,w->b, k ascending)
// is IDENTICAL to the passing kernel -> bit-identical grams -> identical
// top-k / ema / loss.
//
// Staging: register software pipeline (scalar slot vars -- round-11: dynamic
// arrays spilled) across all 32 (layer,chunk) stages; LDS staging tile is
// double-buffered so each stage needs a single __syncthreads.
// Layer order: 7 first (produces insub in-LDS), then 0..6 with rolling
// normalized-gram parity buffer; pairs(p) fires when p,p+1 both resident.
// ---------------------------------------------------------------------------

#define SLOT_DECL(s) int off##s = -1; int lds##s = 0; float4 pre##s;
#define SLOT_SETUP(s) { int idx = tid + (s)*NTH; if (idx < (m << 5)) { \
    int i = idx >> 5, k4 = idx & 31; \
    off##s = (g_s[i] << 9) + (k4 << 2); \
    lds##s = i * 132 + (k4 << 2); } }
#define SLOT_FETCH(s, srcb) if (off##s >= 0) pre##s = *(const float4*)((srcb) + off##s);
#define SLOT_STORE(s) if (off##s >= 0) *(float4*)(Xcur + lds##s) = pre##s;

// 2x2 gram tile slots (static names -- no runtime-indexed arrays).
#define TDECL(s) short ti##s = -1, tj##s = 0; \
    float q##s##00a=0.f,q##s##00b=0.f,q##s##01a=0.f,q##s##01b=0.f, \
          q##s##10a=0.f,q##s##10b=0.f,q##s##11a=0.f,q##s##11b=0.f;

#define TSETUP(s) { int p = tid + (s)*NTH; if (p < TP) { \
    int i = (int)((sqrtf(8.0f * (float)p + 1.0f) - 1.0f) * 0.5f); \
    while (((i + 1) * (i + 2)) / 2 <= p) ++i; \
    while ((i * (i + 1)) / 2 > p) --i; \
    ti##s = (short)i; tj##s = (short)(p - (i * (i + 1)) / 2); } }

#define TCOMP(s) if (ti##s >= 0) { \
    const float* ra = Xcur + ((int)ti##s << 1) * 132; \
    const float* rb = Xcur + ((int)tj##s << 1) * 132; \
    _Pragma("unroll") \
    for (int k4 = 0; k4 < 32; ++k4) { \
        float4 a0v = *(const float4*)(ra + (k4 << 2)); \
        float4 a1v = *(const float4*)(ra + 132 + (k4 << 2)); \
        float4 b0v = *(const float4*)(rb + (k4 << 2)); \
        float4 b1v = *(const float4*)(rb + 132 + (k4 << 2)); \
        q##s##00a = fmaf(a0v.x, b0v.x, q##s##00a); q##s##00b = fmaf(a0v.y, b0v.y, q##s##00b); \
        q##s##00a = fmaf(a0v.z, b0v.z, q##s##00a); q##s##00b = fmaf(a0v.w, b0v.w, q##s##00b); \
        q##s##01a = fmaf(a0v.x, b1v.x, q##s##01a); q##s##01b = fmaf(a0v.y, b1v.y, q##s##01b); \
        q##s##01a = fmaf(a0v.z, b1v.z, q##s##01a); q##s##01b = fmaf(a0v.w, b1v.w, q##s##01b); \
        q##s##10a = fmaf(a1v.x, b0v.x, q##s##10a); q##s##10b = fmaf(a1v.y, b0v.y, q##s##10b); \
        q##s##10a = fmaf(a1v.z, b0v.z, q##s##10a); q##s##10b = fmaf(a1v.w, b0v.w, q##s##10b); \
        q##s##11a = fmaf(a1v.x, b1v.x, q##s##11a); q##s##11b = fmaf(a1v.y, b1v.y, q##s##11b); \
        q##s##11a = fmaf(a1v.z, b1v.z, q##s##11a); q##s##11b = fmaf(a1v.w, b1v.w, q##s##11b); \
    } }

// Symmetric write-back; diag-tile duplicate entries (i,i+1)/(i+1,i) compute
// bit-identical values (fp mul commutes, same accumulation order) -> benign.
#define TWB(s) if (ti##s >= 0) { \
    int ib = (int)ti##s << 1, jb = (int)tj##s << 1; \
    float v00 = q##s##00a + q##s##00b; \
    float v01 = q##s##01a + q##s##01b; \
    float v10 = q##s##10a + q##s##10b; \
    float v11 = q##s##11a + q##s##11b; \
    Gt[ib][jb] = v00; Gt[jb][ib] = v00; \
    if (jb + 1 < m) { Gt[ib][jb+1] = v01; Gt[jb+1][ib] = v01; } \
    if (ib + 1 < m) { Gt[ib+1][jb] = v10; Gt[jb][ib+1] = v10; } \
    if (ib + 1 < m && jb + 1 < m) { Gt[ib+1][jb+1] = v11; Gt[jb+1][ib+1] = v11; } \
    q##s##00a=0.f;q##s##00b=0.f;q##s##01a=0.f;q##s##01b=0.f; \
    q##s##10a=0.f;q##s##10b=0.f;q##s##11a=0.f;q##s##11b=0.f; }

// Masked reduce for one layer-pair p; writes (n,d,cc) partial for (p,c).
__device__ __forceinline__ void pairs_acc(
    int p, int c, int m, int tid,
    const float (*gA)[65], const float (*gB)[65],
    const unsigned long long* MbA, const unsigned long long* MbB,
    const float* es, float* red, float* __restrict__ partial)
{
    float fn = 0.0f, fd = 0.0f, fc = 0.0f;
    for (int idx = tid; idx < (m << 6); idx += NTH) {
        int i = idx >> 6, j = idx & 63;
        if (j >= m) continue;
        bool b0 = (MbA[i] >> j) & 1ull;
        bool b1 = (MbB[i] >> j) & 1ull;
        if (b0 | b1) {
            float v0 = b0 ? gA[i][j] : 0.0f;   // already normalized+clipped
            float v1 = b1 ? gB[i][j] : 0.0f;
            float w = es[i] * es[j];
            float d = v1 - v0;
            fn = fmaf(d * d, w, fn);
            fd += w;
            fc += 1.0f;
        }
    }
    for (int off = 32; off > 0; off >>= 1) {
        fn += __shfl_down(fn, off);
        fd += __shfl_down(fd, off);
        fc += __shfl_down(fc, off);
    }
    int wvx = tid >> 6;
    if ((tid & 63) == 0) { red[wvx*3] = fn; red[wvx*3+1] = fd; red[wvx*3+2] = fc; }
    __syncthreads();
    if (tid == 0) {
        float* dst = partial + ((size_t)p * NLAB + c) * 4;
        dst[0] = red[0] + red[3] + red[6] + red[9];
        dst[1] = red[1] + red[4] + red[7] + red[10];
        dst[2] = red[2] + red[5] + red[8] + red[11];
    }
    __syncthreads();   // red reused by the next pairs_acc call
}

__global__ __launch_bounds__(NTH) void k_fused(
    const float* __restrict__ feats, const int* __restrict__ labels,
    float* __restrict__ partial)
{
    __shared__ int wsum[4];
    __shared__ int g_s[MAXM];
    __shared__ float Xt[2][MAXM][132];          // staging, double-buffered (67.6 KB)
    __shared__ float g2[2][MAXM][65];           // rolling normalized grams, layers 0..6
    __shared__ float g7[MAXM][65];              // normalized layer-7 gram (persists)
    __shared__ float rinv[64];
    __shared__ unsigned long long Mb[NL][64];
    __shared__ float emas[NL][64];
    __shared__ unsigned long long tops_s[64];
    __shared__ unsigned char keep_s[64];
    __shared__ unsigned long long sub_s;
    __shared__ float red[12];

    int c = blockIdx.x, tid = threadIdx.x;
    int lane = tid & 63, wv = tid >> 6;

    // ---- bucket via wave scan (deterministic, index-ascending) ----
    int my[8]; int n = 0; int base_i = tid * 8;
    for (int t = 0; t < 8; ++t) {
        int i = base_i + t;
        if (labels[i] == c) my[n++] = i;
    }
    int scan = n;
    #pragma unroll
    for (int off = 1; off < 64; off <<= 1) {
        int v = __shfl_up(scan, off);
        if (lane >= off) scan += v;
    }
    if (lane == 63) wsum[wv] = scan;
    __syncthreads();
    int w0 = wsum[0], w1 = wsum[1], w2 = wsum[2], w3 = wsum[3];
    int m = w0 + w1 + w2 + w3; if (m > MAXM) m = MAXM;
    int base = (wv > 0 ? w0 : 0) + (wv > 1 ? w1 : 0) + (wv > 2 ? w2 : 0);
    int excl = base + scan - n;
    for (int t = 0; t < n; ++t) {
        int slot = excl + t;
        if (slot < MAXM) g_s[slot] = my[t];
    }
    __syncthreads();
    if (m == 0) {                   // essentially never, but k_final reads all (p,c)
        if (tid == 0) {
            for (int p = 0; p < NL - 1; ++p) {
                float* dst = partial + ((size_t)p * NLAB + c) * 4;
                dst[0] = 0.0f; dst[1] = 0.0f; dst[2] = 0.0f;
            }
        }
        return;
    }

    const size_t LSTR = (size_t)NB * ND;

    // ---- staging slots; prefetch stage 0 (layer 7, chunk 0) ----
    SLOT_DECL(0) SLOT_DECL(1) SLOT_DECL(2) SLOT_DECL(3)
    SLOT_DECL(4) SLOT_DECL(5) SLOT_DECL(6) SLOT_DECL(7)
    SLOT_SETUP(0) SLOT_SETUP(1) SLOT_SETUP(2) SLOT_SETUP(3)
    SLOT_SETUP(4) SLOT_SETUP(5) SLOT_SETUP(6) SLOT_SETUP(7)
    {
        const float* xb = feats + (size_t)7 * LSTR;
        SLOT_FETCH(0, xb) SLOT_FETCH(1, xb) SLOT_FETCH(2, xb) SLOT_FETCH(3, xb)
        SLOT_FETCH(4, xb) SLOT_FETCH(5, xb) SLOT_FETCH(6, xb) SLOT_FETCH(7, xb)
    }

    // ---- 2x2 tile decode (overlaps chunk-0 load latency) ----
    const int R = (m + 1) >> 1;
    const int TP = R * (R + 1) / 2;
    TDECL(0) TDECL(1) TDECL(2)
    TSETUP(0) TSETUP(1) TSETUP(2)

    // ---- 32-stage pipeline: stage t = (stage-layer t>>2, chunk t&3) ----
    // stage-layer sl: 0 -> layer 7, sl>=1 -> layer sl-1.
    for (int t = 0; t < 32; ++t) {
        float* Xcur = &Xt[t & 1][0][0];
        SLOT_STORE(0) SLOT_STORE(1) SLOT_STORE(2) SLOT_STORE(3)
        SLOT_STORE(4) SLOT_STORE(5) SLOT_STORE(6) SLOT_STORE(7)
        __syncthreads();
        if (t < 31) {
            int tn = t + 1;
            int Ln = ((tn >> 2) == 0) ? 7 : (tn >> 2) - 1;
            const float* xb = feats + (size_t)Ln * LSTR + ((tn & 3) << 7);
            SLOT_FETCH(0, xb) SLOT_FETCH(1, xb) SLOT_FETCH(2, xb) SLOT_FETCH(3, xb)
            SLOT_FETCH(4, xb) SLOT_FETCH(5, xb) SLOT_FETCH(6, xb) SLOT_FETCH(7, xb)
        }
        TCOMP(0) TCOMP(1) TCOMP(2)

        if ((t & 3) == 3) {
            int sl = t >> 2;
            int L = (sl == 0) ? 7 : sl - 1;
            float (*Gt)[65] = (sl == 0) ? g7 : g2[L & 1];

            // raw gram write + acc reset
            TWB(0) TWB(1) TWB(2)
            __syncthreads();
            if (tid < 64) rinv[tid] = (tid < m) ? 1.0f / fmaxf(sqrtf(Gt[tid][tid]), 1e-8f) : 0.0f;
            __syncthreads();
            // normalize+clip in place; sentinel -2 for cols >= m (rows >= m never read)
            for (int idx = tid; idx < (m << 6); idx += NTH) {
                int i = idx >> 6, j = idx & 63;
                float x = -2.0f;
                if (j < m) {
                    float raw = Gt[i][j];
                    x = fminf(fmaxf(raw * rinv[i] * rinv[j], -1.0f), 1.0f);
                }
                Gt[i][j] = x;
            }
            __syncthreads();

            if (sl == 0) {
                // ---- phase-1: full-group knn on layer 7 -> insub bits ----
                if (tid < 64) { keep_s[tid] = 0; tops_s[tid] = 0ull; }
                __syncthreads();
                unsigned long long tops = 0ull; bool keep = false;
                if (tid < m) {
                    float v0=-1.f,v1=-1.f,v2=-1.f,v3=-1.f,v4=-1.f;
                    int i0=0,i1=0,i2=0,i3=0,i4=0, cand=0;
                    #pragma unroll 8
                    for (int j = 0; j < 64; ++j) {
                        float v = g7[tid][j];
                        if (v > 0.0f && j != tid) {
                            ++cand;
                            if      (v > v0) { v4=v3;i4=i3; v3=v2;i3=i2; v2=v1;i2=i1; v1=v0;i1=i0; v0=v;i0=j; }
                            else if (v > v1) { v4=v3;i4=i3; v3=v2;i3=i2; v2=v1;i2=i1; v1=v;i1=j; }
                            else if (v > v2) { v4=v3;i4=i3; v3=v2;i3=i2; v2=v;i2=j; }
                            else if (v > v3) { v4=v3;i4=i3; v3=v;i3=j; }
                            else if (v > v4) { v4=v;i4=j; }
                        }
                    }
                    keep = (cand >= TOPK_);
                    if (keep) tops = (1ull<<i0)|(1ull<<i1)|(1ull<<i2)|(1ull<<i3)|(1ull<<i4);
                    keep_s[tid] = keep ? 1 : 0; tops_s[tid] = tops;
                }
                __syncthreads();
                unsigned long long Mrow = 0ull;
                if (tid < m && keep) {
                    for (int j = 0; j < 64; ++j) {
                        if (j == tid || !keep_s[j]) continue;
                        if (((tops >> j) & 1ull) || ((tops_s[j] >> tid) & 1ull)) Mrow |= (1ull << j);
                    }
                }
                if (tid < 64) {
                    unsigned long long b = __ballot(Mrow != 0ull);
                    if (tid == 0) sub_s = b;
                }
                __syncthreads();
            }

            // ---- decide(L): subset-restricted knn -> Mb[L], emas[L] ----
            if (tid < 64) { keep_s[tid] = 0; tops_s[tid] = 0ull; }
            __syncthreads();
            {
                unsigned long long sub = sub_s;
                unsigned long long tops = 0ull; bool keep = false; float emaval = 0.0f;
                if (tid < m) {
                    bool act = (sub >> tid) & 1ull;
                    if (act) {
                        float v0=-1.f,v1=-1.f,v2=-1.f,v3=-1.f,v4=-1.f;
                        int i0=0,i1=0,i2=0,i3=0,i4=0, cand=0, dg=0;
                        float rs = 0.0f;
                        #pragma unroll 8
                        for (int j = 0; j < 64; ++j) {
                            float v = Gt[tid][j];
                            if (!((sub >> j) & 1ull)) v = -2.0f;
                            if (v > 0.0f) {
                                rs += v; ++dg;              // includes j == tid (diag ~ 1.0)
                                if (j != tid) {
                                    ++cand;
                                    if      (v > v0) { v4=v3;i4=i3; v3=v2;i3=i2; v2=v1;i2=i1; v1=v0;i1=i0; v0=v;i0=j; }
                                    else if (v > v1) { v4=v3;i4=i3; v3=v2;i3=i2; v2=v1;i2=i1; v1=v;i1=j; }
                                    else if (v > v2) { v4=v3;i4=i3; v3=v2;i3=i2; v2=v;i2=j; }
                                    else if (v > v3) { v4=v3;i4=i3; v3=v;i3=j; }
                                    else if (v > v4) { v4=v;i4=j; }
                                }
                            }
                        }
                        keep = (cand >= TOPK_);
                        if (keep) tops = (1ull<<i0)|(1ull<<i1)|(1ull<<i2)|(1ull<<i3)|(1ull<<i4);
                        float deg = (float)(dg > 0 ? dg : 1);
                        float score = 1.0f / (1.0f + expf(-rs / deg));
                        emaval = 0.45f + 0.1f * score;      // MOM*0.5 + (1-MOM)*score
                    }
                    keep_s[tid] = keep ? 1 : 0; tops_s[tid] = tops;
                }
                __syncthreads();
                if (tid < m) {
                    unsigned long long Mrow = 0ull;
                    if (keep) {
                        for (int j = 0; j < 64; ++j) {
                            if (j == tid || !keep_s[j]) continue;
                            if (((tops >> j) & 1ull) || ((tops_s[j] >> tid) & 1ull)) Mrow |= (1ull << j);
                        }
                    }
                    Mb[L][tid] = Mrow;
                    emas[L][tid] = emaval;
                }
                __syncthreads();
            }

            // ---- pairs(L-1) once both layers resident (L = 1..6) ----
            if (sl >= 2) {
                pairs_acc(L - 1, c, m, tid,
                          (const float (*)[65])g2[(L - 1) & 1],
                          (const float (*)[65])g2[L & 1],
                          Mb[L - 1], Mb[L], emas[L - 1], red, partial);
            }
        }
    }
    // ---- pairs(6): layer 6 (g2[0]) vs layer 7 (g7) ----
    pairs_acc(6, c, m, tid,
              (const float (*)[65])g2[0], (const float (*)[65])g7,
              Mb[6], Mb[7], emas[6], red, partial);
}

// Single-wave final reduction: cross-label num/den ratio per layer-pair.
// Identical summation order to the passing 4-kernel version (bit-match).
__global__ void k_final(const float* __restrict__ partial, float* __restrict__ out)
{
    int tid = threadIdx.x;
    float total = 0.0f;
    for (int p = 0; p < NL - 1; ++p) {
        float n = 0.0f, d = 0.0f, cc = 0.0f;
        for (int c = tid; c < NLAB; c += 64) {
            const float* src = partial + ((size_t)p * NLAB + c) * 4;
            n += src[0]; d += src[1]; cc += src[2];
        }
        for (int off = 32; off > 0; off >>= 1) {
            n += __shfl_down(n, off);
            d += __shfl_down(d, off);
            cc += __shfl_down(cc, off);
        }
        if (tid == 0 && cc > 0.0f) total += n / fmaxf(d, 1e-8f);
    }
    if (tid == 0) out[0] = 16.0f * total / 7.0f;   // LAMBDA_ALIGN_K * sum / (L-1)
}

extern "C" void kernel_launch(void* const* d_in, const int* in_sizes, int n_in,
                              void* d_out, int out_size, void* d_ws, size_t ws_size,
                              hipStream_t stream) {
    const float* feats  = (const float*)d_in[0];
    const int*   labels = (const int*)d_in[1];
    // (sample_ids unused by the reference)
    float* partial = (float*)d_ws;     // [NL-1][NLAB][4] = 14,336 B
    float* out     = (float*)d_out;

    k_fused<<<dim3(NLAB), NTH, 0, stream>>>(feats, labels, partial);
    k_final<<<1, 64, 0, stream>>>(partial, out);
}

// Round 2
// 129.306 us; speedup vs baseline: 2.0750x; 2.0750x over previous
//
#include <hip/hip_runtime.h>
#include <cmath>

#define NB   2048
#define ND   512
#define NL   8
#define NLAB 128
#define MAXM 64
#define TOPK_ 5
#define NTH  256
#define MAXSLOT 9            // ceil(64*65/2 / 256)
#define GSTRIDE (MAXM*MAXM)  // 4096 floats per (label,layer) gram

// ---------------------------------------------------------------------------
// R13 post-mortem of R12: full per-label fusion collapsed parallelism (128
// blocks, ~1 active wave each, Occupancy 2.7%, 215us). Revert to wide grids;
// remove redundancy instead:
//   k_gram (128x8): proven pipeline; NOW normalizes the gram in LDS and
//     stores normalized G (coalesced rows). Layer-7 blocks keep fused phase-1.
//   k_pairdec (128x7): loads two normalized tiles, runs decide(p) on wave 0
//     and decide(p+1) on wave 1 concurrently (decide is deterministic from
//     normalized G + insub -> duplication across pair-blocks is bit-safe),
//     then the masked pair reduce from LDS. Deletes k_decide, its 16.7MB G
//     re-read, and the Mbits/ema global round-trip.
// All FP expressions keep the exact op order of the passing 4-kernel version
// (normalize: clip((raw*ri)*rj); reduce order unchanged) -> absmax 0.0.
// ---------------------------------------------------------------------------
#define SLOT_DECL(s) int off##s = -1; int lds##s = 0; float4 pre##s;
#define SLOT_INIT(s) { int idx = tid + (s)*NTH; if (idx < (m << 5)) { \
    int i = idx >> 5, k4 = idx & 31; \
    off##s = (g_s[i] << 9) + (k4 << 2); \
    lds##s = i * 132 + (k4 << 2); \
    pre##s = *(const float4*)(X + off##s); } }
#define SLOT_STORE(s) if (off##s >= 0) *(float4*)(XtF + lds##s) = pre##s;
#define SLOT_FETCH(s, kcn) if (off##s >= 0) pre##s = *(const float4*)(X + off##s + (kcn));

__global__ __launch_bounds__(NTH) void k_gram(
    const float* __restrict__ feats, const int* __restrict__ labels,
    float* __restrict__ G, int* __restrict__ cnt,
    unsigned long long* __restrict__ insub)
{
    __shared__ int wsum[4];
    __shared__ int g_s[MAXM];
    __shared__ float Xt[MAXM][132];   // 132%4==0 -> aligned float4 rows; reused as 64x65 tile
    __shared__ float rinvp[64];
    __shared__ unsigned long long tops_s[64];
    __shared__ unsigned char keep_s[64];
    float* XtF = &Xt[0][0];
    int c = blockIdx.x, l = blockIdx.y, tid = threadIdx.x;
    int lane = tid & 63, wv = tid >> 6;

    // ---- bucket via wave scan (deterministic, index-ascending) ----
    int my[8]; int n = 0; int base_i = tid * 8;
    for (int t = 0; t < 8; ++t) {
        int i = base_i + t;
        if (labels[i] == c) my[n++] = i;
    }
    int scan = n;
    #pragma unroll
    for (int off = 1; off < 64; off <<= 1) {
        int v = __shfl_up(scan, off);
        if (lane >= off) scan += v;
    }
    if (lane == 63) wsum[wv] = scan;
    __syncthreads();
    int w0 = wsum[0], w1 = wsum[1], w2 = wsum[2], w3 = wsum[3];
    int m = w0 + w1 + w2 + w3; if (m > MAXM) m = MAXM;
    int base = (wv > 0 ? w0 : 0) + (wv > 1 ? w1 : 0) + (wv > 2 ? w2 : 0);
    int excl = base + scan - n;
    for (int t = 0; t < n; ++t) {
        int slot = excl + t;
        if (slot < MAXM) g_s[slot] = my[t];
    }
    if (l == 0 && tid == 0) cnt[c] = m;
    __syncthreads();
    if (m == 0) {
        if (l == 7 && tid == 0) insub[c] = 0ull;
        return;
    }

    const float* X = feats + (size_t)l * NB * ND;

    // ---- scalar staging slots; prefetch chunk 0 ----
    SLOT_DECL(0) SLOT_DECL(1) SLOT_DECL(2) SLOT_DECL(3)
    SLOT_DECL(4) SLOT_DECL(5) SLOT_DECL(6) SLOT_DECL(7)
    SLOT_INIT(0) SLOT_INIT(1) SLOT_INIT(2) SLOT_INIT(3)
    SLOT_INIT(4) SLOT_INIT(5) SLOT_INIT(6) SLOT_INIT(7)

    // ---- triangular slot decode (overlaps chunk-0 load latency) ----
    const int P = m * (m + 1) / 2;    // triangular incl. diag
    float acc0[MAXSLOT], acc1[MAXSLOT];
    short is_[MAXSLOT], js_[MAXSLOT];
    int ns = 0;
    for (int p = tid; p < P; p += NTH) {
        int i = (int)((sqrtf(8.0f * (float)p + 1.0f) - 1.0f) * 0.5f);
        while (((i + 1) * (i + 2)) / 2 <= p) ++i;
        while ((i * (i + 1)) / 2 > p) --i;
        is_[ns] = (short)i;
        js_[ns] = (short)(p - (i * (i + 1)) / 2);
        acc0[ns] = 0.0f; acc1[ns] = 0.0f;
        ++ns;
    }

    // ---- pipelined K-loop: store staged regs, prefetch next, compute ----
    for (int kc = 0; kc < ND; kc += 128) {
        if (kc) __syncthreads();      // previous chunk's readers done
        SLOT_STORE(0) SLOT_STORE(1) SLOT_STORE(2) SLOT_STORE(3)
        SLOT_STORE(4) SLOT_STORE(5) SLOT_STORE(6) SLOT_STORE(7)
        __syncthreads();
        if (kc + 128 < ND) {
            int kcn = kc + 128;
            SLOT_FETCH(0, kcn) SLOT_FETCH(1, kcn) SLOT_FETCH(2, kcn) SLOT_FETCH(3, kcn)
            SLOT_FETCH(4, kcn) SLOT_FETCH(5, kcn) SLOT_FETCH(6, kcn) SLOT_FETCH(7, kcn)
        }
        for (int s = 0; s < ns; ++s) {
            int i = is_[s], j = js_[s];
            float a0 = acc0[s], a1 = acc1[s];
            #pragma unroll
            for (int k4 = 0; k4 < 32; ++k4) {
                float4 a = *(const float4*)&Xt[i][k4 << 2];
                float4 b = *(const float4*)&Xt[j][k4 << 2];
                a0 = fmaf(a.x, b.x, a0); a1 = fmaf(a.y, b.y, a1);
                a0 = fmaf(a.z, b.z, a0); a1 = fmaf(a.w, b.w, a1);
            }
            acc0[s] = a0; acc1[s] = a1;
        }
    }

    // ---- stage raw tile in LDS (reuse Xt), normalize in place, store ----
    float (*Gs)[65] = (float(*)[65])(&Xt[0][0]);
    __syncthreads();                  // all Xt readers done before overwrite
    for (int s = 0; s < ns; ++s) {
        int i = is_[s], j = js_[s];
        float v = acc0[s] + acc1[s];
        Gs[i][j] = v; Gs[j][i] = v;
    }
    if (tid < m) for (int j = m; j < 64; ++j) Gs[tid][j] = -2.0f;  // sentinel cols
    __syncthreads();
    if (tid < 64) rinvp[tid] = (tid < m) ? 1.0f / fmaxf(sqrtf(Gs[tid][tid]), 1e-8f) : 0.0f;
    __syncthreads();
    // normalize+clip in place: clip((raw*ri)*rj) -- exact op order of load_tile
    for (int idx = tid; idx < (m << 6); idx += NTH) {
        int i = idx >> 6, j = idx & 63;
        if (j < m) {
            float raw = Gs[i][j];
            Gs[i][j] = fminf(fmaxf(raw * rinvp[i] * rinvp[j], -1.0f), 1.0f);
        }
    }
    __syncthreads();
    // coalesced row write of the m live rows (cols >= m carry sentinel -2)
    float* Gc = G + ((size_t)l * NLAB + c) * GSTRIDE;
    for (int idx4 = tid; idx4 < (m << 4); idx4 += NTH) {
        int i = idx4 >> 4, j0 = (idx4 & 15) << 2;
        *(float4*)(Gc + i * MAXM + j0) = *(const float4*)&Gs[i][j0];
    }
    if (l != 7) return;

    // ---------- fused phase-1 (layer-7 blocks only), from normalized tile ----
    if (tid < 64) { keep_s[tid] = 0; tops_s[tid] = 0ull; }
    __syncthreads();
    unsigned long long tops = 0ull; bool keep = false;
    if (tid < m) {
        float v0=-1.f,v1=-1.f,v2=-1.f,v3=-1.f,v4=-1.f;
        int i0=0,i1=0,i2=0,i3=0,i4=0, cand=0;
        #pragma unroll 8
        for (int j = 0; j < 64; ++j) {
            float v = Gs[tid][j];          // normalized, or -2 sentinel
            if (v > 0.0f && j != tid) {
                ++cand;
                if      (v > v0) { v4=v3;i4=i3; v3=v2;i3=i2; v2=v1;i2=i1; v1=v0;i1=i0; v0=v;i0=j; }
                else if (v > v1) { v4=v3;i4=i3; v3=v2;i3=i2; v2=v1;i2=i1; v1=v;i1=j; }
                else if (v > v2) { v4=v3;i4=i3; v3=v2;i3=i2; v2=v;i2=j; }
                else if (v > v3) { v4=v3;i4=i3; v3=v;i3=j; }
                else if (v > v4) { v4=v;i4=j; }
            }
        }
        keep = (cand >= TOPK_);
        if (keep) tops = (1ull<<i0)|(1ull<<i1)|(1ull<<i2)|(1ull<<i3)|(1ull<<i4);
        keep_s[tid] = keep ? 1 : 0; tops_s[tid] = tops;
    }
    __syncthreads();
    unsigned long long Mrow = 0ull;
    if (tid < m && keep) {
        for (int j = 0; j < 64; ++j) {
            if (j == tid || !keep_s[j]) continue;
            if (((tops >> j) & 1ull) || ((tops_s[j] >> tid) & 1ull)) Mrow |= (1ull << j);
        }
    }
    if (tid < 64) {
        unsigned long long b = __ballot(Mrow != 0ull);
        if (tid == 0) insub[c] = b;
    }
}

// ---------------------------------------------------------------------------
// Per (label, pair p): load normalized tiles for layers p,p+1; decide(p) on
// wave 0 and decide(p+1) on wave 1 concurrently; masked pair reduce from LDS.
// ---------------------------------------------------------------------------
__global__ __launch_bounds__(NTH) void k_pairdec(
    const float* __restrict__ G, const int* __restrict__ cnt,
    const unsigned long long* __restrict__ insub,
    float* __restrict__ partial)   // [NL-1][NLAB][4]
{
    __shared__ float Gs0[64][65];
    __shared__ float Gs1[64][65];
    __shared__ unsigned long long tops0[64], tops1[64];
    __shared__ unsigned char keep0[64], keep1[64];
    __shared__ unsigned long long M0s[64], M1s[64];
    __shared__ float es[64];
    __shared__ float red[12];      // 4 waves x 3
    int c = blockIdx.x, p = blockIdx.y, tid = threadIdx.x;
    int lane = tid & 63, wv = tid >> 6;
    int m = cnt[c]; if (m > MAXM) m = MAXM;
    unsigned long long sub = insub[c];

    const float* G0 = G + ((size_t)p       * NLAB + c) * GSTRIDE;
    const float* G1 = G + ((size_t)(p + 1) * NLAB + c) * GSTRIDE;
    // load the two normalized tiles (m live rows x 16 float4 each)
    for (int idx4 = tid; idx4 < (m << 4); idx4 += NTH) {
        int i = idx4 >> 4, j0 = (idx4 & 15) << 2;
        *(float4*)&Gs0[i][j0] = *(const float4*)(G0 + i * MAXM + j0);
        *(float4*)&Gs1[i][j0] = *(const float4*)(G1 + i * MAXM + j0);
    }
    if (tid < 64)       { keep0[tid] = 0; tops0[tid] = 0ull; }
    else if (tid < 128) { keep1[tid - 64] = 0; tops1[tid - 64] = 0ull; }
    __syncthreads();

    // ---- decide: wave 0 -> layer p (also ema), wave 1 -> layer p+1 ----
    unsigned long long tops = 0ull; bool keep = false;
    if (wv < 2 && lane < m) {
        const float (*Gt)[65] = (wv == 0) ? Gs0 : Gs1;
        bool act = (sub >> lane) & 1ull;
        float emaval = 0.0f;
        if (act) {
            float v0=-1.f,v1=-1.f,v2=-1.f,v3=-1.f,v4=-1.f;
            int i0=0,i1=0,i2=0,i3=0,i4=0, cand=0, dg=0;
            float rs = 0.0f;
            #pragma unroll 8
            for (int j = 0; j < 64; ++j) {
                float v = Gt[lane][j];
                if (!((sub >> j) & 1ull)) v = -2.0f;
                if (v > 0.0f) {
                    rs += v; ++dg;                  // includes j == lane (diag ~ 1.0)
                    if (j != lane) {
                        ++cand;
                        if      (v > v0) { v4=v3;i4=i3; v3=v2;i3=i2; v2=v1;i2=i1; v1=v0;i1=i0; v0=v;i0=j; }
                        else if (v > v1) { v4=v3;i4=i3; v3=v2;i3=i2; v2=v1;i2=i1; v1=v;i1=j; }
                        else if (v > v2) { v4=v3;i4=i3; v3=v2;i3=i2; v2=v;i2=j; }
                        else if (v > v3) { v4=v3;i4=i3; v3=v;i3=j; }
                        else if (v > v4) { v4=v;i4=j; }
                    }
                }
            }
            keep = (cand >= TOPK_);
            if (keep) tops = (1ull<<i0)|(1ull<<i1)|(1ull<<i2)|(1ull<<i3)|(1ull<<i4);
            float deg = (float)(dg > 0 ? dg : 1);
            float score = 1.0f / (1.0f + expf(-rs / deg));
            emaval = 0.45f + 0.1f * score;          // MOM*0.5 + (1-MOM)*score
        }
        if (wv == 0) { keep0[lane] = keep ? 1 : 0; tops0[lane] = tops; es[lane] = emaval; }
        else         { keep1[lane] = keep ? 1 : 0; tops1[lane] = tops; }
    }
    __syncthreads();
    if (wv < 2 && lane < m) {
        const unsigned long long* topsW = (wv == 0) ? tops0 : tops1;
        const unsigned char*     keepW = (wv == 0) ? keep0 : keep1;
        unsigned long long Mrow = 0ull;
        if (keep) {
            for (int j = 0; j < 64; ++j) {
                if (j == lane || !keepW[j]) continue;
                if (((tops >> j) & 1ull) || ((topsW[j] >> lane) & 1ull)) Mrow |= (1ull << j);
            }
        }
        if (wv == 0) M0s[lane] = Mrow; else M1s[lane] = Mrow;
    }
    __syncthreads();

    // ---- masked reduce (identical loop + reduce order to passing k_pairs) ----
    float fn = 0.0f, fd = 0.0f, fc = 0.0f;
    for (int idx = tid; idx < (m << 6); idx += NTH) {
        int i = idx >> 6, j = idx & 63;
        if (j >= m) continue;
        bool b0 = (M0s[i] >> j) & 1ull;
        bool b1 = (M1s[i] >> j) & 1ull;
        if (b0 | b1) {
            float v0 = b0 ? Gs0[i][j] : 0.0f;   // normalized+clipped in k_gram
            float v1 = b1 ? Gs1[i][j] : 0.0f;
            float w = es[i] * es[j];
            float d = v1 - v0;
            fn = fmaf(d * d, w, fn);
            fd += w;
            fc += 1.0f;
        }
    }
    for (int off = 32; off > 0; off >>= 1) {
        fn += __shfl_down(fn, off);
        fd += __shfl_down(fd, off);
        fc += __shfl_down(fc, off);
    }
    if ((tid & 63) == 0) { red[wv * 3] = fn; red[wv * 3 + 1] = fd; red[wv * 3 + 2] = fc; }
    __syncthreads();
    if (tid == 0) {
        float* dst = partial + ((size_t)p * NLAB + c) * 4;
        dst[0] = red[0] + red[3] + red[6] + red[9];
        dst[1] = red[1] + red[4] + red[7] + red[10];
        dst[2] = red[2] + red[5] + red[8] + red[11];
    }
}

// Single-wave final reduction over 896 private slots (~14 KB, L2-hit).
__global__ void k_final(const float* __restrict__ partial, float* __restrict__ out)
{
    int tid = threadIdx.x;
    float total = 0.0f;
    for (int p = 0; p < NL - 1; ++p) {
        float n = 0.0f, d = 0.0f, cc = 0.0f;
        for (int c = tid; c < NLAB; c += 64) {
            const float* src = partial + ((size_t)p * NLAB + c) * 4;
            n += src[0]; d += src[1]; cc += src[2];
        }
        for (int off = 32; off > 0; off >>= 1) {
            n += __shfl_down(n, off);
            d += __shfl_down(d, off);
            cc += __shfl_down(cc, off);
        }
        if (tid == 0 && cc > 0.0f) total += n / fmaxf(d, 1e-8f);
    }
    if (tid == 0) out[0] = 16.0f * total / 7.0f;   // LAMBDA_ALIGN_K * sum / (L-1)
}

extern "C" void kernel_launch(void* const* d_in, const int* in_sizes, int n_in,
                              void* d_out, int out_size, void* d_ws, size_t ws_size,
                              hipStream_t stream) {
    const float* feats  = (const float*)d_in[0];
    const int*   labels = (const int*)d_in[1];
    // (sample_ids unused by the reference)
    char* w = (char*)d_ws;
    size_t gbytes = (size_t)NL * NLAB * GSTRIDE * 4;                 // 16,777,216
    float*    G       = (float*)(w);                                 // normalized grams
    float*    partial = (float*)(w + gbytes);                        // 14,336 B
    int*      cnt     = (int*)(w + gbytes + 14336);                  // 512 B
    unsigned long long* insub = (unsigned long long*)(w + gbytes + 14848);   // 1,024 B
    float*    out     = (float*)d_out;

    k_gram   <<<dim3(NLAB, NL),     NTH, 0, stream>>>(feats, labels, G, cnt, insub);
    k_pairdec<<<dim3(NLAB, NL - 1), NTH, 0, stream>>>(G, cnt, insub, partial);
    k_final  <<<1, 64, 0, stream>>>(partial, out);
}